// Round 9
// baseline (513.651 us; speedup 1.0000x reference)
//
#include <hip/hip_runtime.h>
#include <hip/hip_bf16.h>

// Problem constants (match reference setup_inputs)
#define NN 30000      // nodes
#define NE 600000     // edges
#define DD 128        // feature dim
#define RR 7          // relations
#define GG 16         // graphs
#define LL 3          // layers

#define NB64 ((NN + 63) / 64)   // 469 buckets of 64 nodes (sort granularity)
#define NROW (NB64 * 64)        // 30016 padded rows
#define NB32 (NROW / 32)        // 938 fused-layer blocks (32 dest nodes each)
#define MSTR 904                // LDS msg row stride (ushorts): 452 dw ≡ 4 mod 32 -> 2-way only

typedef short bf16x8 __attribute__((ext_vector_type(8)));  // 8 bf16 = 4 VGPRs
typedef float f32x4  __attribute__((ext_vector_type(4)));

// ---- bf16 helpers ----------------------------------------------------------
__device__ __forceinline__ unsigned short f2bf(float f) {
    unsigned u = __float_as_uint(f);
    unsigned r = (u + 0x7fffu + ((u >> 16) & 1u)) >> 16;
    return (unsigned short)r;
}
__device__ __forceinline__ ushort2 pk2bf(float a, float b) {
    __hip_bfloat162 t = __float22bfloat162_rn(make_float2(a, b));
    return *(ushort2*)&t;
}

// ---------------------------------------------------------------------------
// Weight pack: Bw2[l][kc][n][k'] (bf16) with B[k][n] = Wr[l][k][n] (k<896)
// else Wl[l][k-896][n];  k = kc*128 + k'. Also zeros bcnt (runs before hist).
// ---------------------------------------------------------------------------
__global__ __launch_bounds__(256) void pack_weights(
    const float* __restrict__ Wl,   // L x 128 x 128
    const float* __restrict__ Wr,   // L x 896 x 128
    unsigned short* __restrict__ Bw2,// L x 8 x 128 x 128
    int* __restrict__ bcnt)
{
    int t = blockIdx.x * 256 + threadIdx.x;
    if (t < NB64 * 16) bcnt[t] = 0;
    if (t >= LL * 8 * DD * DD) return;
    int kp = t & 127;
    int n  = (t >> 7) & 127;
    int kc = (t >> 14) & 7;
    int l  = t >> 17;
    int k  = kc * 128 + kp;
    float v;
    if (k < RR * DD) v = Wr[(size_t)l * RR * DD * DD + (size_t)k * DD + n];
    else             v = Wl[(size_t)l * DD * DD + (size_t)(k - RR * DD) * DD + n];
    Bw2[(size_t)l * 8 * DD * DD + (size_t)kc * DD * DD + n * DD + kp] = f2bf(v);
}

// x (fp32) -> bf16; block 0 also zeros gf (16x128 floats)
__global__ __launch_bounds__(256) void convert_bf16(
    const float* __restrict__ in, unsigned short* __restrict__ out,
    float* __restrict__ gf, int n4)
{
    int i = blockIdx.x * 256 + threadIdx.x;
    if (blockIdx.x == 0) {
#pragma unroll
        for (int j = 0; j < 8; ++j) gf[threadIdx.x + j * 256] = 0.f;
    }
    if (i >= n4) return;
    float4 v = ((const float4*)in)[i];
    ushort2 lo = pk2bf(v.x, v.y);
    ushort2 hi = pk2bf(v.z, v.w);
    ((ushort4*)out)[i] = make_ushort4(lo.x, lo.y, hi.x, hi.y);
}

// ---------------------------------------------------------------------------
// Bucketed edge sort. Bucket = 64 dest nodes; within bucket sort by
// key = (dest&63)<<3 | rel (512 bins). Emits meta=((src<<7)|rel, ew) grouped
// by (dest,rel) and start2[node*8 + r] (slot 7 = end of node's edges).
// start2 is written for ALL NROW padded nodes (pad nodes -> empty ranges).
// ---------------------------------------------------------------------------
__global__ __launch_bounds__(256) void bucket_hist(
    const int* __restrict__ node_out, int* __restrict__ bcnt, int E)
{
    int e = blockIdx.x * 256 + threadIdx.x;
    if (e < E) atomicAdd(&bcnt[(node_out[e] >> 6) * 16], 1);
}

__global__ __launch_bounds__(512) void bucket_scan(
    const int* __restrict__ bcnt, int* __restrict__ bstart,
    int* __restrict__ bcur, int nb)
{
    __shared__ int s[512];
    int t = threadIdx.x;
    int v = (t < nb) ? bcnt[t * 16] : 0;
    s[t] = v;
    __syncthreads();
#pragma unroll
    for (int off = 1; off < 512; off <<= 1) {
        int u = (t >= off) ? s[t - off] : 0;
        __syncthreads();
        s[t] += u;
        __syncthreads();
    }
    if (t <= nb) {
        int excl = s[t] - v;
        bstart[t] = excl;
        if (t < nb) bcur[t * 16] = excl;
    }
}

// pack.x = (out&63)<<21 | rel<<18 | src   (src < 2^18)
__global__ __launch_bounds__(256) void bucket_scatter(
    const int* __restrict__ node_in,
    const int* __restrict__ node_out,
    const int* __restrict__ relation,
    const float* __restrict__ ew,
    int* __restrict__ bcur,
    int2* __restrict__ tmp,
    int E)
{
    int e = blockIdx.x * 256 + threadIdx.x;
    if (e >= E) return;
    int o = node_out[e];
    int pos = atomicAdd(&bcur[(o >> 6) * 16], 1);
    tmp[pos] = make_int2(((o & 63) << 21) | (relation[e] << 18) | node_in[e],
                         __float_as_int(ew[e]));
}

__global__ __launch_bounds__(256) void bucket_sort(
    const int2* __restrict__ tmp,
    const int* __restrict__ bstart,
    int2* __restrict__ meta,
    int* __restrict__ start2,   // NROW*8
    int N)
{
    __shared__ int hist[512];
    __shared__ int excl[512];
    __shared__ int cur[512];
    __shared__ int ssum[256];
    const int b = blockIdx.x;
    const int t = threadIdx.x;
    const int s0 = bstart[b];
    const int s1 = bstart[b + 1];

    hist[t] = 0; hist[t + 256] = 0;
    __syncthreads();
    for (int i = s0 + t; i < s1; i += 256)
        atomicAdd(&hist[((unsigned)tmp[i].x) >> 18], 1);
    __syncthreads();

    int a0 = hist[2 * t], a1 = hist[2 * t + 1];
    ssum[t] = a0 + a1;
    __syncthreads();
#pragma unroll
    for (int off = 1; off < 256; off <<= 1) {
        int u = (t >= off) ? ssum[t - off] : 0;
        __syncthreads();
        ssum[t] += u;
        __syncthreads();
    }
    int base = (t == 0) ? 0 : ssum[t - 1];
    excl[2 * t] = base;
    excl[2 * t + 1] = base + a0;
    cur[2 * t] = s0 + base;
    cur[2 * t + 1] = s0 + base + a0;
    __syncthreads();

    {
        // write start2 for ALL 64 local nodes (pad nodes get empty ranges)
        int k0 = 2 * t, k1 = 2 * t + 1;
        int n0 = b * 64 + (k0 >> 3), n1 = b * 64 + (k1 >> 3);
        start2[n0 * 8 + (k0 & 7)] = s0 + excl[k0];
        start2[n1 * 8 + (k1 & 7)] = s0 + excl[k1];
    }
    __syncthreads();

    for (int i = s0 + t; i < s1; i += 256) {
        int2 m = tmp[i];
        int key = ((unsigned)m.x) >> 18;
        int pos = atomicAdd(&cur[key], 1);
        int src = m.x & 0x3ffff;
        int rel = key & 7;
        meta[pos] = make_int2((src << 7) | rel, m.y);
    }
}

// ---------------------------------------------------------------------------
// fused_layer: per block of 32 dest nodes,
//   phase 1: msgT[local][rel*128+c] = sum_e w_e * h[src_e][c]   (LDS only)
//   phase 2: out = relu([msgT | h] (32 x 1024) @ Bw2 (1024 x 128) + br + bl)
// 512 threads = 8 waves. Phase 1: wave w gathers nodes w*4..w*4+3 (flat edge
// loop, 14 fp32 accs, unroll-8 MLP). Phase 2: wave (rg,cg) owns 16 rows x 32
// cols; A from LDS (stride 904 -> 2-way banks only), B register-prefetched
// from L2-resident packed weights; h-chunk (kc=7) read direct from global L2.
// msg NEVER touches global memory.
// ---------------------------------------------------------------------------
__global__ __launch_bounds__(512, 4) void fused_layer(
    const unsigned short* __restrict__ hb,    // NROW x 128 bf16
    const int* __restrict__ start2,           // NROW*8
    const int2* __restrict__ meta,            // E
    const unsigned short* __restrict__ Bw2l,  // 8 x 128 x 128 bf16 (kc,n,k')
    const float* __restrict__ br,             // 128
    const float* __restrict__ bl,             // 128
    unsigned short* __restrict__ out_bf16,    // NROW x 128 or null
    float* __restrict__ out_f32,              // N x 128 or null
    int N)
{
    __shared__ unsigned short msgT[32 * MSTR];   // 57,856 B

    const int tid  = threadIdx.x;
    const int w    = tid >> 6;
    const int lane = tid & 63;
    const int quad = lane >> 4;
    const int l16  = lane & 15;
    const int row0 = blockIdx.x * 32;

    // ---------------- phase 1: gather ----------------
#define ACCUM(MX, MY, UU) {                                                  \
    float wt = __int_as_float(MY);                                           \
    float fx = __uint_as_float((UU) << 16);                                  \
    float fy = __uint_as_float((UU) & 0xffff0000u);                          \
    int r = (MX) & 7;                                                        \
    if (r == 0)      { ax0 = fmaf(wt, fx, ax0); ay0 = fmaf(wt, fy, ay0); }   \
    else if (r == 1) { ax1 = fmaf(wt, fx, ax1); ay1 = fmaf(wt, fy, ay1); }   \
    else if (r == 2) { ax2 = fmaf(wt, fx, ax2); ay2 = fmaf(wt, fy, ay2); }   \
    else if (r == 3) { ax3 = fmaf(wt, fx, ax3); ay3 = fmaf(wt, fy, ay3); }   \
    else if (r == 4) { ax4 = fmaf(wt, fx, ax4); ay4 = fmaf(wt, fy, ay4); }   \
    else if (r == 5) { ax5 = fmaf(wt, fx, ax5); ay5 = fmaf(wt, fy, ay5); }   \
    else             { ax6 = fmaf(wt, fx, ax6); ay6 = fmaf(wt, fy, ay6); } }

    for (int i = 0; i < 4; ++i) {
        int local = w * 4 + i;
        int nd = row0 + local;
        int e0 = start2[nd * 8];
        int e1 = start2[nd * 8 + 7];

        float ax0 = 0.f, ay0 = 0.f, ax1 = 0.f, ay1 = 0.f, ax2 = 0.f, ay2 = 0.f;
        float ax3 = 0.f, ay3 = 0.f, ax4 = 0.f, ay4 = 0.f, ax5 = 0.f, ay5 = 0.f;
        float ax6 = 0.f, ay6 = 0.f;

        int e = e0;
        for (; e + 8 <= e1; e += 8) {
            int2 m[8]; unsigned u[8];
#pragma unroll
            for (int j = 0; j < 8; ++j) m[j] = meta[e + j];
#pragma unroll
            for (int j = 0; j < 8; ++j)
                u[j] = *(const unsigned*)(hb + (m[j].x & ~127) + lane * 2);
#pragma unroll
            for (int j = 0; j < 8; ++j) ACCUM(m[j].x, m[j].y, u[j]);
        }
        for (; e + 2 <= e1; e += 2) {
            int2 m0 = meta[e], m1 = meta[e + 1];
            unsigned u0 = *(const unsigned*)(hb + (m0.x & ~127) + lane * 2);
            unsigned u1 = *(const unsigned*)(hb + (m1.x & ~127) + lane * 2);
            ACCUM(m0.x, m0.y, u0);
            ACCUM(m1.x, m1.y, u1);
        }
        if (e < e1) {
            int2 m = meta[e];
            unsigned u = *(const unsigned*)(hb + (m.x & ~127) + lane * 2);
            ACCUM(m.x, m.y, u);
        }

        unsigned short* mrow = msgT + local * MSTR + lane * 2;
        *(ushort2*)(mrow + 0 * DD) = pk2bf(ax0, ay0);
        *(ushort2*)(mrow + 1 * DD) = pk2bf(ax1, ay1);
        *(ushort2*)(mrow + 2 * DD) = pk2bf(ax2, ay2);
        *(ushort2*)(mrow + 3 * DD) = pk2bf(ax3, ay3);
        *(ushort2*)(mrow + 4 * DD) = pk2bf(ax4, ay4);
        *(ushort2*)(mrow + 5 * DD) = pk2bf(ax5, ay5);
        *(ushort2*)(mrow + 6 * DD) = pk2bf(ax6, ay6);
    }
#undef ACCUM
    __syncthreads();

    // ---------------- phase 2: GEMM ----------------
    const int rg = w >> 2;                   // 0..1 (16-row group)
    const int cg = w & 3;                    // 0..3 (32-col group)
    const int ncol = cg * 32 + l16;

    f32x4 acc0 = (f32x4){0.f, 0.f, 0.f, 0.f};
    f32x4 acc1 = (f32x4){0.f, 0.f, 0.f, 0.f};

    const unsigned short* als    = msgT + (rg * 16 + l16) * MSTR;
    const unsigned short* arow_g = hb + (size_t)(row0 + rg * 16 + l16) * DD;

    // software-pipelined B prefetch (registers, L2-resident weights)
    bf16x8 b0 = *(const bf16x8*)(Bw2l + (size_t)ncol * DD + quad * 8);
    bf16x8 b1 = *(const bf16x8*)(Bw2l + (size_t)(ncol + 16) * DD + quad * 8);
#pragma unroll
    for (int t = 0; t < 32; ++t) {
        const int kc = t >> 2, kci = t & 3;
        bf16x8 nb0 = b0, nb1 = b1;
        if (t < 31) {
            const int nk = t + 1;
            const unsigned short* bp =
                Bw2l + (size_t)(nk >> 2) * (DD * DD) + (nk & 3) * 32 + quad * 8;
            nb0 = *(const bf16x8*)(bp + (size_t)ncol * DD);
            nb1 = *(const bf16x8*)(bp + (size_t)(ncol + 16) * DD);
        }
        bf16x8 a;
        if (kc < 7) a = *(const bf16x8*)(als + kc * 128 + kci * 32 + quad * 8);
        else        a = *(const bf16x8*)(arow_g + kci * 32 + quad * 8);
        acc0 = __builtin_amdgcn_mfma_f32_16x16x32_bf16(a, b0, acc0, 0, 0, 0);
        acc1 = __builtin_amdgcn_mfma_f32_16x16x32_bf16(a, b1, acc1, 0, 0, 0);
        b0 = nb0; b1 = nb1;
    }

    float bias0 = br[ncol] + bl[ncol];
    float bias1 = br[ncol + 16] + bl[ncol + 16];
#pragma unroll
    for (int reg = 0; reg < 4; ++reg) {
        int row = row0 + rg * 16 + quad * 4 + reg;
        float v0 = fmaxf(acc0[reg] + bias0, 0.f);
        float v1 = fmaxf(acc1[reg] + bias1, 0.f);
        if (out_bf16) {
            ushort2 p = pk2bf(v0, v1);
            out_bf16[(size_t)row * DD + ncol]      = p.x;
            out_bf16[(size_t)row * DD + ncol + 16] = p.y;
        }
        if (out_f32 && row < N) {
            out_f32[(size_t)row * DD + ncol]      = v0;
            out_f32[(size_t)row * DD + ncol + 16] = v1;
        }
    }
}

// ---------------------------------------------------------------------------
// Graph segment sum: gf[n2g[n]] += nf[n] (n2g sorted).
// ---------------------------------------------------------------------------
__global__ __launch_bounds__(256) void graph_sum(
    const float* __restrict__ nf,
    const int* __restrict__ n2g,
    float* __restrict__ gf,
    int N)
{
    int t = blockIdx.x * 256 + threadIdx.x;
    int chunk = t >> 5;
    int lane = t & 31;
    int n0 = chunk * 16;
    if (n0 >= N) return;
    int nend = n0 + 16; if (nend > N) nend = N;

    float4 acc = make_float4(0.f, 0.f, 0.f, 0.f);
    int curg = n2g[n0];
    for (int n = n0; n < nend; ++n) {
        int g = n2g[n];
        if (g != curg) {
            float* dst = gf + (size_t)curg * DD + lane * 4;
            atomicAdd(dst + 0, acc.x); atomicAdd(dst + 1, acc.y);
            atomicAdd(dst + 2, acc.z); atomicAdd(dst + 3, acc.w);
            acc = make_float4(0.f, 0.f, 0.f, 0.f);
            curg = g;
        }
        float4 v = *(const float4*)(nf + (size_t)n * DD + lane * 4);
        acc.x += v.x; acc.y += v.y; acc.z += v.z; acc.w += v.w;
    }
    float* dst = gf + (size_t)curg * DD + lane * 4;
    atomicAdd(dst + 0, acc.x); atomicAdd(dst + 1, acc.y);
    atomicAdd(dst + 2, acc.z); atomicAdd(dst + 3, acc.w);
}

// ---------------------------------------------------------------------------
extern "C" void kernel_launch(void* const* d_in, const int* in_sizes, int n_in,
                              void* d_out, int out_size, void* d_ws, size_t ws_size,
                              hipStream_t stream)
{
    const float* x        = (const float*)d_in[0];
    const int*   node_in  = (const int*)d_in[1];
    const int*   node_out = (const int*)d_in[2];
    const int*   relation = (const int*)d_in[3];
    const float* ew       = (const float*)d_in[4];
    const int*   n2g      = (const int*)d_in[5];
    const float* Wr       = (const float*)d_in[6];
    const float* br       = (const float*)d_in[7];
    const float* Wl       = (const float*)d_in[8];
    const float* bl       = (const float*)d_in[9];

    float* out = (float*)d_out;
    float* gf = out;                 // 16 x 128
    float* nf = out + GG * DD;       // 30000 x 128

    // Workspace layout (~27 MB — msg now lives in LDS)
    char* w = (char*)d_ws;
    unsigned short* hbA  = (unsigned short*)w; w += (size_t)NROW * DD * 2;      // 7.7 MB
    unsigned short* hbB  = (unsigned short*)w; w += (size_t)NROW * DD * 2;      // 7.7 MB
    unsigned short* Bw2  = (unsigned short*)w; w += (size_t)LL * 8 * DD * DD * 2; // 0.79 MB
    int2*  meta   = (int2*)w;                  w += (size_t)NE * 8;             // 4.8 MB
    int2*  tmp    = (int2*)w;                  w += (size_t)NE * 8;             // 4.8 MB
    int*   start2 = (int*)w;                   w += (size_t)NROW * 8 * 4;       // 0.96 MB
    int*   bcnt   = (int*)w;                   w += (size_t)NB64 * 16 * 4 + 64;
    int*   bcur   = (int*)w;                   w += (size_t)NB64 * 16 * 4 + 64;
    int*   bstart = (int*)w;                   w += (size_t)(NB64 + 1) * 4 + 60;

    const int N = NN, E = NE;

    // ---- once per call: weight pack (+bcnt zero), x->bf16 (+gf zero), sort -
    pack_weights<<<(LL * 8 * DD * DD + 255) / 256, 256, 0, stream>>>(Wl, Wr, Bw2, bcnt);
    convert_bf16<<<(N * DD / 4 + 255) / 256, 256, 0, stream>>>(x, hbA, gf, N * DD / 4);

    bucket_hist<<<(E + 255) / 256, 256, 0, stream>>>(node_out, bcnt, E);
    bucket_scan<<<1, 512, 0, stream>>>(bcnt, bstart, bcur, NB64);
    bucket_scatter<<<(E + 255) / 256, 256, 0, stream>>>(
        node_in, node_out, relation, ew, bcur, tmp, E);
    bucket_sort<<<NB64, 256, 0, stream>>>(tmp, bstart, meta, start2, N);

    // ---- layers (fused aggregate+GEMM) ----
    unsigned short* hin = hbA;
    unsigned short* hnext = hbB;
    for (int l = 0; l < LL; ++l) {
        const float* br_l = br + (size_t)l * DD;
        const float* bl_l = bl + (size_t)l * DD;
        const unsigned short* Bw2_l = Bw2 + (size_t)l * 8 * DD * DD;

        bool last = (l == LL - 1);
        fused_layer<<<NB32, 512, 0, stream>>>(
            hin, start2, meta, Bw2_l, br_l, bl_l,
            last ? (unsigned short*)nullptr : hnext,
            last ? nf : (float*)nullptr, N);

        unsigned short* t = hin; hin = hnext; hnext = t;
    }

    // ---- graph_feature ----
    int chunks = (N + 15) / 16;
    graph_sum<<<(chunks * 32 + 255) / 256, 256, 0, stream>>>(nf, n2g, gf, N);
}

// Round 10
// 372.088 us; speedup vs baseline: 1.3805x; 1.3805x over previous
//
#include <hip/hip_runtime.h>
#include <hip/hip_bf16.h>

// Problem constants (match reference setup_inputs)
#define NN 30000      // nodes
#define NE 600000     // edges
#define DD 128        // feature dim
#define RR 7          // relations
#define GG 16         // graphs
#define LL 3          // layers

#define NB64 ((NN + 63) / 64)   // 469 buckets of 64 nodes (sort granularity)
#define NROW (NB64 * 64)        // 30016 padded rows
#define NB32 (NROW / 32)        // 938 gemm3 blocks (32 rows each)
#define MS   (RR * DD)          // 896 msg row stride

typedef short bf16x8 __attribute__((ext_vector_type(8)));  // 8 bf16 = 4 VGPRs
typedef float f32x4  __attribute__((ext_vector_type(4)));

// ---- bf16 helpers ----------------------------------------------------------
__device__ __forceinline__ unsigned short f2bf(float f) {
    unsigned u = __float_as_uint(f);
    unsigned r = (u + 0x7fffu + ((u >> 16) & 1u)) >> 16;
    return (unsigned short)r;
}
__device__ __forceinline__ ushort2 pk2bf(float a, float b) {
    __hip_bfloat162 t = __float22bfloat162_rn(make_float2(a, b));
    return *(ushort2*)&t;
}

// ---------------------------------------------------------------------------
// Weight pack: Bw2[l][kc][n][k'] (bf16) with B[k][n] = Wr[l][k][n] (k<896)
// else Wl[l][k-896][n];  k = kc*128 + k'. Also zeros bcnt (runs before hist).
// ---------------------------------------------------------------------------
__global__ __launch_bounds__(256) void pack_weights(
    const float* __restrict__ Wl,   // L x 128 x 128
    const float* __restrict__ Wr,   // L x 896 x 128
    unsigned short* __restrict__ Bw2,// L x 8 x 128 x 128
    int* __restrict__ bcnt)
{
    int t = blockIdx.x * 256 + threadIdx.x;
    if (t < NB64 * 16) bcnt[t] = 0;
    if (t >= LL * 8 * DD * DD) return;
    int kp = t & 127;
    int n  = (t >> 7) & 127;
    int kc = (t >> 14) & 7;
    int l  = t >> 17;
    int k  = kc * 128 + kp;
    float v;
    if (k < MS) v = Wr[(size_t)l * MS * DD + (size_t)k * DD + n];
    else        v = Wl[(size_t)l * DD * DD + (size_t)(k - MS) * DD + n];
    Bw2[(size_t)l * 8 * DD * DD + (size_t)kc * DD * DD + n * DD + kp] = f2bf(v);
}

// x (fp32) -> bf16; block 0 also zeros gf (16x128 floats)
__global__ __launch_bounds__(256) void convert_bf16(
    const float* __restrict__ in, unsigned short* __restrict__ out,
    float* __restrict__ gf, int n4)
{
    int i = blockIdx.x * 256 + threadIdx.x;
    if (blockIdx.x == 0) {
#pragma unroll
        for (int j = 0; j < 8; ++j) gf[threadIdx.x + j * 256] = 0.f;
    }
    if (i >= n4) return;
    float4 v = ((const float4*)in)[i];
    ushort2 lo = pk2bf(v.x, v.y);
    ushort2 hi = pk2bf(v.z, v.w);
    ((ushort4*)out)[i] = make_ushort4(lo.x, lo.y, hi.x, hi.y);
}

// ---------------------------------------------------------------------------
// Bucketed edge sort. Bucket = 64 dest nodes; within bucket sort by
// key = (dest&63)<<3 | rel (512 bins). Emits meta=((src<<7)|rel, ew) grouped
// by (dest,rel) and start2[node*8 + r] (slot 7 = end of node's edges).
// ---------------------------------------------------------------------------
__global__ __launch_bounds__(256) void bucket_hist(
    const int* __restrict__ node_out, int* __restrict__ bcnt, int E)
{
    int e = blockIdx.x * 256 + threadIdx.x;
    if (e < E) atomicAdd(&bcnt[(node_out[e] >> 6) * 16], 1);
}

__global__ __launch_bounds__(512) void bucket_scan(
    const int* __restrict__ bcnt, int* __restrict__ bstart,
    int* __restrict__ bcur, int nb)
{
    __shared__ int s[512];
    int t = threadIdx.x;
    int v = (t < nb) ? bcnt[t * 16] : 0;
    s[t] = v;
    __syncthreads();
#pragma unroll
    for (int off = 1; off < 512; off <<= 1) {
        int u = (t >= off) ? s[t - off] : 0;
        __syncthreads();
        s[t] += u;
        __syncthreads();
    }
    if (t <= nb) {
        int excl = s[t] - v;
        bstart[t] = excl;
        if (t < nb) bcur[t * 16] = excl;
    }
}

// pack.x = (out&63)<<21 | rel<<18 | src   (src < 2^18)
__global__ __launch_bounds__(256) void bucket_scatter(
    const int* __restrict__ node_in,
    const int* __restrict__ node_out,
    const int* __restrict__ relation,
    const float* __restrict__ ew,
    int* __restrict__ bcur,
    int2* __restrict__ tmp,
    int E)
{
    int e = blockIdx.x * 256 + threadIdx.x;
    if (e >= E) return;
    int o = node_out[e];
    int pos = atomicAdd(&bcur[(o >> 6) * 16], 1);
    tmp[pos] = make_int2(((o & 63) << 21) | (relation[e] << 18) | node_in[e],
                         __float_as_int(ew[e]));
}

__global__ __launch_bounds__(256) void bucket_sort(
    const int2* __restrict__ tmp,
    const int* __restrict__ bstart,
    int2* __restrict__ meta,
    int* __restrict__ start2,   // NROW*8
    int N)
{
    __shared__ int hist[512];
    __shared__ int excl[512];
    __shared__ int cur[512];
    __shared__ int ssum[256];
    const int b = blockIdx.x;
    const int t = threadIdx.x;
    const int s0 = bstart[b];
    const int s1 = bstart[b + 1];

    hist[t] = 0; hist[t + 256] = 0;
    __syncthreads();
    for (int i = s0 + t; i < s1; i += 256)
        atomicAdd(&hist[((unsigned)tmp[i].x) >> 18], 1);
    __syncthreads();

    int a0 = hist[2 * t], a1 = hist[2 * t + 1];
    ssum[t] = a0 + a1;
    __syncthreads();
#pragma unroll
    for (int off = 1; off < 256; off <<= 1) {
        int u = (t >= off) ? ssum[t - off] : 0;
        __syncthreads();
        ssum[t] += u;
        __syncthreads();
    }
    int base = (t == 0) ? 0 : ssum[t - 1];
    excl[2 * t] = base;
    excl[2 * t + 1] = base + a0;
    cur[2 * t] = s0 + base;
    cur[2 * t + 1] = s0 + base + a0;
    __syncthreads();

    {
        // write start2 for ALL 64 local nodes (pad nodes get empty ranges)
        int k0 = 2 * t, k1 = 2 * t + 1;
        int n0 = b * 64 + (k0 >> 3), n1 = b * 64 + (k1 >> 3);
        start2[n0 * 8 + (k0 & 7)] = s0 + excl[k0];
        start2[n1 * 8 + (k1 & 7)] = s0 + excl[k1];
    }
    __syncthreads();

    for (int i = s0 + t; i < s1; i += 256) {
        int2 m = tmp[i];
        int key = ((unsigned)m.x) >> 18;
        int pos = atomicAdd(&cur[key], 1);
        int src = m.x & 0x3ffff;
        int rel = key & 7;
        meta[pos] = make_int2((src << 7) | rel, m.y);
    }
}

// ---------------------------------------------------------------------------
// aggregate_msg: msg[d][r][:] = sum_{e in seg(d,r)} ew_e * h[src_e][:]
// One 64-lane wave per dest node; lane owns 2 columns (14 fp32 accs).
// Wave-uniform scalars forced via readfirstlane so meta reads go to the
// scalar pipe; 16 outstanding gathers in the main loop.
// ---------------------------------------------------------------------------
__global__ __launch_bounds__(256) void aggregate_msg(
    const unsigned short* __restrict__ hb,   // NROW x 128 bf16
    const int* __restrict__ start2,          // NROW*8
    const int2* __restrict__ meta,           // E
    unsigned short* __restrict__ msg,        // NROW x 896 bf16
    int N)
{
    int wid = (blockIdx.x * 256 + threadIdx.x) >> 6;
    wid = __builtin_amdgcn_readfirstlane(wid);
    int lane = threadIdx.x & 63;
    if (wid >= N) return;

    int e0 = __builtin_amdgcn_readfirstlane(start2[wid * 8]);
    int e1 = __builtin_amdgcn_readfirstlane(start2[wid * 8 + 7]);

    float ax0 = 0.f, ay0 = 0.f, ax1 = 0.f, ay1 = 0.f, ax2 = 0.f, ay2 = 0.f;
    float ax3 = 0.f, ay3 = 0.f, ax4 = 0.f, ay4 = 0.f, ax5 = 0.f, ay5 = 0.f;
    float ax6 = 0.f, ay6 = 0.f;

#define ACCUM(MX, MY, UU) {                                                  \
    float wt = __int_as_float(MY);                                           \
    float fx = __uint_as_float((UU) << 16);                                  \
    float fy = __uint_as_float((UU) & 0xffff0000u);                          \
    int r = (MX) & 7;                                                        \
    if (r == 0)      { ax0 = fmaf(wt, fx, ax0); ay0 = fmaf(wt, fy, ay0); }   \
    else if (r == 1) { ax1 = fmaf(wt, fx, ax1); ay1 = fmaf(wt, fy, ay1); }   \
    else if (r == 2) { ax2 = fmaf(wt, fx, ax2); ay2 = fmaf(wt, fy, ay2); }   \
    else if (r == 3) { ax3 = fmaf(wt, fx, ax3); ay3 = fmaf(wt, fy, ay3); }   \
    else if (r == 4) { ax4 = fmaf(wt, fx, ax4); ay4 = fmaf(wt, fy, ay4); }   \
    else if (r == 5) { ax5 = fmaf(wt, fx, ax5); ay5 = fmaf(wt, fy, ay5); }   \
    else             { ax6 = fmaf(wt, fx, ax6); ay6 = fmaf(wt, fy, ay6); } }

    int e = e0;
    for (; e + 16 <= e1; e += 16) {
        int2 m[16]; unsigned u[16];
#pragma unroll
        for (int j = 0; j < 16; ++j) m[j] = meta[e + j];
#pragma unroll
        for (int j = 0; j < 16; ++j)
            u[j] = *(const unsigned*)(hb + (m[j].x & ~127) + lane * 2);
#pragma unroll
        for (int j = 0; j < 16; ++j) ACCUM(m[j].x, m[j].y, u[j]);
    }
    for (; e + 4 <= e1; e += 4) {
        int2 m[4]; unsigned u[4];
#pragma unroll
        for (int j = 0; j < 4; ++j) m[j] = meta[e + j];
#pragma unroll
        for (int j = 0; j < 4; ++j)
            u[j] = *(const unsigned*)(hb + (m[j].x & ~127) + lane * 2);
#pragma unroll
        for (int j = 0; j < 4; ++j) ACCUM(m[j].x, m[j].y, u[j]);
    }
    for (; e < e1; ++e) {
        int2 m = meta[e];
        unsigned u = *(const unsigned*)(hb + (m.x & ~127) + lane * 2);
        ACCUM(m.x, m.y, u);
    }
#undef ACCUM

    unsigned short* mrow = msg + (size_t)wid * MS + lane * 2;
    *(ushort2*)(mrow + 0 * DD) = pk2bf(ax0, ay0);
    *(ushort2*)(mrow + 1 * DD) = pk2bf(ax1, ay1);
    *(ushort2*)(mrow + 2 * DD) = pk2bf(ax2, ay2);
    *(ushort2*)(mrow + 3 * DD) = pk2bf(ax3, ay3);
    *(ushort2*)(mrow + 4 * DD) = pk2bf(ax4, ay4);
    *(ushort2*)(mrow + 5 * DD) = pk2bf(ax5, ay5);
    *(ushort2*)(mrow + 6 * DD) = pk2bf(ax6, ay6);
}

// ---------------------------------------------------------------------------
// gemm3: h' = relu([msg | h] (N x 1024) @ Bw2 (1024 x 128) + br + bl)
// 938 blocks x 256 threads (4 waves). Block owns 32 rows x 128 cols; K=1024
// in 8 chunks of 128. A chunk staged ONCE into LDS (stride 136 -> 2-way banks
// only, free); B fragments read per-wave from L2-resident packed weights.
// ~8 blocks/CU co-resident -> barrier drains overlap across blocks.
// ---------------------------------------------------------------------------
#define ASTR3 136
__global__ __launch_bounds__(256) void gemm3(
    const unsigned short* __restrict__ msg,  // NROW x 896 bf16
    const unsigned short* __restrict__ hb,   // NROW x 128 bf16
    const unsigned short* __restrict__ Bw2l, // 8 x 128 x 128 bf16 (kc,n,k')
    const float* __restrict__ br,            // 128
    const float* __restrict__ bl,            // 128
    unsigned short* __restrict__ out_bf16,   // NROW x 128 or null
    float* __restrict__ out_f32,             // N x 128 or null
    int N)
{
    __shared__ unsigned short As[32 * ASTR3];   // 8704 B

    const int tid  = threadIdx.x;
    const int wave = tid >> 6;
    const int lane = tid & 63;
    const int quad = lane >> 4;
    const int l16  = lane & 15;
    const int row0 = blockIdx.x * 32;
    const int ncol = wave * 32 + l16;

    f32x4 acc00 = (f32x4){0.f, 0.f, 0.f, 0.f};   // rows 0-15,  cols ncol
    f32x4 acc01 = (f32x4){0.f, 0.f, 0.f, 0.f};   // rows 0-15,  cols ncol+16
    f32x4 acc10 = (f32x4){0.f, 0.f, 0.f, 0.f};   // rows 16-31, cols ncol
    f32x4 acc11 = (f32x4){0.f, 0.f, 0.f, 0.f};   // rows 16-31, cols ncol+16

#pragma unroll
    for (int kc = 0; kc < 8; ++kc) {
        // ---- stage A chunk: 32 rows x 128 ushorts (8 KB), 2 int4/thread ----
        const unsigned short* asrc;
        int astr;
        if (kc < 7) { asrc = msg + (size_t)row0 * MS + kc * 128; astr = MS; }
        else        { asrc = hb  + (size_t)row0 * DD;            astr = DD; }
#pragma unroll
        for (int i = 0; i < 2; ++i) {
            int f = tid + i * 256;            // 0..511
            int r = f >> 4;                   // 16 int4 per row
            int c = f & 15;
            int4 v = *(const int4*)(asrc + (size_t)r * astr + c * 8);
            *(int4*)(As + r * ASTR3 + c * 8) = v;
        }
        __syncthreads();

        const unsigned short* bsrc = Bw2l + (size_t)kc * DD * DD;
#pragma unroll
        for (int kci = 0; kci < 4; ++kci) {
            int ko = kci * 32 + quad * 8;
            bf16x8 a0 = *(const bf16x8*)(As + l16 * ASTR3 + ko);
            bf16x8 a1 = *(const bf16x8*)(As + (16 + l16) * ASTR3 + ko);
            bf16x8 b0 = *(const bf16x8*)(bsrc + (size_t)ncol * DD + ko);
            bf16x8 b1 = *(const bf16x8*)(bsrc + (size_t)(ncol + 16) * DD + ko);
            acc00 = __builtin_amdgcn_mfma_f32_16x16x32_bf16(a0, b0, acc00, 0, 0, 0);
            acc01 = __builtin_amdgcn_mfma_f32_16x16x32_bf16(a0, b1, acc01, 0, 0, 0);
            acc10 = __builtin_amdgcn_mfma_f32_16x16x32_bf16(a1, b0, acc10, 0, 0, 0);
            acc11 = __builtin_amdgcn_mfma_f32_16x16x32_bf16(a1, b1, acc11, 0, 0, 0);
        }
        __syncthreads();
    }

    float bias0 = br[ncol] + bl[ncol];
    float bias1 = br[ncol + 16] + bl[ncol + 16];
#pragma unroll
    for (int reg = 0; reg < 4; ++reg) {
        int r0 = row0 + quad * 4 + reg;       // rows 0-15 tile
        int r1 = r0 + 16;                     // rows 16-31 tile
        float v00 = fmaxf(acc00[reg] + bias0, 0.f);
        float v01 = fmaxf(acc01[reg] + bias1, 0.f);
        float v10 = fmaxf(acc10[reg] + bias0, 0.f);
        float v11 = fmaxf(acc11[reg] + bias1, 0.f);
        if (out_bf16) {
            ushort2 p0 = pk2bf(v00, v01);
            ushort2 p1 = pk2bf(v10, v11);
            out_bf16[(size_t)r0 * DD + ncol]      = p0.x;
            out_bf16[(size_t)r0 * DD + ncol + 16] = p0.y;
            out_bf16[(size_t)r1 * DD + ncol]      = p1.x;
            out_bf16[(size_t)r1 * DD + ncol + 16] = p1.y;
        }
        if (out_f32) {
            if (r0 < N) {
                out_f32[(size_t)r0 * DD + ncol]      = v00;
                out_f32[(size_t)r0 * DD + ncol + 16] = v01;
            }
            if (r1 < N) {
                out_f32[(size_t)r1 * DD + ncol]      = v10;
                out_f32[(size_t)r1 * DD + ncol + 16] = v11;
            }
        }
    }
}

// ---------------------------------------------------------------------------
// Graph segment sum: gf[n2g[n]] += nf[n] (n2g sorted).
// ---------------------------------------------------------------------------
__global__ __launch_bounds__(256) void graph_sum(
    const float* __restrict__ nf,
    const int* __restrict__ n2g,
    float* __restrict__ gf,
    int N)
{
    int t = blockIdx.x * 256 + threadIdx.x;
    int chunk = t >> 5;
    int lane = t & 31;
    int n0 = chunk * 16;
    if (n0 >= N) return;
    int nend = n0 + 16; if (nend > N) nend = N;

    float4 acc = make_float4(0.f, 0.f, 0.f, 0.f);
    int curg = n2g[n0];
    for (int n = n0; n < nend; ++n) {
        int g = n2g[n];
        if (g != curg) {
            float* dst = gf + (size_t)curg * DD + lane * 4;
            atomicAdd(dst + 0, acc.x); atomicAdd(dst + 1, acc.y);
            atomicAdd(dst + 2, acc.z); atomicAdd(dst + 3, acc.w);
            acc = make_float4(0.f, 0.f, 0.f, 0.f);
            curg = g;
        }
        float4 v = *(const float4*)(nf + (size_t)n * DD + lane * 4);
        acc.x += v.x; acc.y += v.y; acc.z += v.z; acc.w += v.w;
    }
    float* dst = gf + (size_t)curg * DD + lane * 4;
    atomicAdd(dst + 0, acc.x); atomicAdd(dst + 1, acc.y);
    atomicAdd(dst + 2, acc.z); atomicAdd(dst + 3, acc.w);
}

// ---------------------------------------------------------------------------
extern "C" void kernel_launch(void* const* d_in, const int* in_sizes, int n_in,
                              void* d_out, int out_size, void* d_ws, size_t ws_size,
                              hipStream_t stream)
{
    const float* x        = (const float*)d_in[0];
    const int*   node_in  = (const int*)d_in[1];
    const int*   node_out = (const int*)d_in[2];
    const int*   relation = (const int*)d_in[3];
    const float* ew       = (const float*)d_in[4];
    const int*   n2g      = (const int*)d_in[5];
    const float* Wr       = (const float*)d_in[6];
    const float* br       = (const float*)d_in[7];
    const float* Wl       = (const float*)d_in[8];
    const float* bl       = (const float*)d_in[9];

    float* out = (float*)d_out;
    float* gf = out;                 // 16 x 128
    float* nf = out + GG * DD;       // 30000 x 128

    // Workspace layout (~82 MB)
    char* w = (char*)d_ws;
    unsigned short* msg  = (unsigned short*)w; w += (size_t)NROW * MS * 2;      // 53.8 MB
    unsigned short* hbA  = (unsigned short*)w; w += (size_t)NROW * DD * 2;      // 7.7 MB
    unsigned short* hbB  = (unsigned short*)w; w += (size_t)NROW * DD * 2;      // 7.7 MB
    unsigned short* Bw2  = (unsigned short*)w; w += (size_t)LL * 8 * DD * DD * 2; // 0.79 MB
    int2*  meta   = (int2*)w;                  w += (size_t)NE * 8;             // 4.8 MB
    int2*  tmp    = (int2*)w;                  w += (size_t)NE * 8;             // 4.8 MB
    int*   start2 = (int*)w;                   w += (size_t)NROW * 8 * 4;       // 0.96 MB
    int*   bcnt   = (int*)w;                   w += (size_t)NB64 * 16 * 4 + 64;
    int*   bcur   = (int*)w;                   w += (size_t)NB64 * 16 * 4 + 64;
    int*   bstart = (int*)w;                   w += (size_t)(NB64 + 1) * 4 + 60;

    const int N = NN, E = NE;

    // ---- once per call: weight pack (+bcnt zero), x->bf16 (+gf zero), sort -
    pack_weights<<<(LL * 8 * DD * DD + 255) / 256, 256, 0, stream>>>(Wl, Wr, Bw2, bcnt);
    convert_bf16<<<(N * DD / 4 + 255) / 256, 256, 0, stream>>>(x, hbA, gf, N * DD / 4);

    bucket_hist<<<(E + 255) / 256, 256, 0, stream>>>(node_out, bcnt, E);
    bucket_scan<<<1, 512, 0, stream>>>(bcnt, bstart, bcur, NB64);
    bucket_scatter<<<(E + 255) / 256, 256, 0, stream>>>(
        node_in, node_out, relation, ew, bcur, tmp, E);
    bucket_sort<<<NB64, 256, 0, stream>>>(tmp, bstart, meta, start2, N);

    // ---- layers ----
    unsigned short* hin = hbA;
    unsigned short* hnext = hbB;
    for (int l = 0; l < LL; ++l) {
        const float* br_l = br + (size_t)l * DD;
        const float* bl_l = bl + (size_t)l * DD;
        const unsigned short* Bw2_l = Bw2 + (size_t)l * 8 * DD * DD;

        aggregate_msg<<<(N * 64 + 255) / 256, 256, 0, stream>>>(
            hin, start2, meta, msg, N);

        bool last = (l == LL - 1);
        gemm3<<<NB32, 256, 0, stream>>>(
            msg, hin, Bw2_l, br_l, bl_l,
            last ? (unsigned short*)nullptr : hnext,
            last ? nf : (float*)nullptr, N);

        unsigned short* t = hin; hin = hnext; hnext = t;
    }

    // ---- graph_feature ----
    int chunks = (N + 15) / 16;
    graph_sum<<<(chunks * 32 + 255) / 256, 256, 0, stream>>>(nf, n2g, gf, N);
}